// Round 8
// baseline (448.951 us; speedup 1.0000x reference)
//
#include <hip/hip_runtime.h>

#define LN_EPS 1e-5f

typedef __attribute__((ext_vector_type(8))) short bf16x8;
typedef __attribute__((ext_vector_type(8))) short s16x8;
typedef __attribute__((ext_vector_type(4))) float f32x4;

__device__ __forceinline__ unsigned short f2bf(float f){
  unsigned u = __builtin_bit_cast(unsigned, f);
  u = (u + 0x7fffu + ((u >> 16) & 1u)) >> 16;
  return (unsigned short)u;
}
__device__ __forceinline__ void gll16(const void* g, void* l){
  __builtin_amdgcn_global_load_lds(
      (const __attribute__((address_space(1))) unsigned int*)(g),
      (__attribute__((address_space(3))) unsigned int*)(l), 16, 0, 0);
}

// ---------------------------------------------------------------------------
// Kernel A (merged): z<24 -> cond LN + K/V projection; z==24 -> WqT prep.
// WqT[n][d ^ ((n>>1)&3)<<3] = bf16(Wq[d][n])   (slot-swizzled, R4-validated)
// ---------------------------------------------------------------------------
__global__ void k_aux(const float* __restrict__ Wq,
                      unsigned short* __restrict__ WqT,
                      const float* __restrict__ cond, const int* __restrict__ idx,
                      const float* __restrict__ tg, const float* __restrict__ tb,
                      const float* __restrict__ Wk, const float* __restrict__ bk,
                      const float* __restrict__ Wv, const float* __restrict__ bv,
                      float* __restrict__ kbuf, float* __restrict__ vbuf)
{
  __shared__ float cn[16][768];
  const int tid = threadIdx.x;

  if(blockIdx.z == 24){
    // ---- prep role: 16 of the 20 (x,y) blocks; block owns 32 n-columns ----
    const int pb = blockIdx.x + 4*blockIdx.y;
    if(pb >= 16) return;
    const int c = tid & 31, q = tid >> 5;          // q = d-rowgroup (64 d's)
    const int n = pb*32 + c;
    const int swz = (n >> 1) & 3;
    for(int i=0;i<64;i+=4){
      ushort4 pkv;
      unsigned short* pp = (unsigned short*)&pkv;
      #pragma unroll
      for(int j=0;j<4;j++){
        const int d = q*64 + i + j;
        pp[j] = f2bf(Wq[(size_t)d*512 + n]);
      }
      *(ushort4*)(WqT + (size_t)n*512 + ((q*64 + i) ^ (swz << 3))) = pkv;
    }
    return;
  }

  // ---- condkv role (unchanged, validated) ----
  const int bc = blockIdx.z, nc = blockIdx.y, dc = blockIdx.x;
  const int b = idx[bc];
  const int n0 = nc * 16;
  int nrows = 77 - n0; if(nrows > 16) nrows = 16;
  const int w = tid >> 6, lane = tid & 63;

  for(int r = w; r < nrows; r += 4){
    const float* src = cond + ((size_t)b * 77 + n0 + r) * 768;
    float vals[12]; float s1 = 0.f, s2 = 0.f;
    #pragma unroll
    for(int i=0;i<12;i++){ float x = src[lane + i*64]; vals[i]=x; s1+=x; s2+=x*x; }
    #pragma unroll
    for(int off=1; off<64; off<<=1){ s1 += __shfl_xor(s1, off); s2 += __shfl_xor(s2, off); }
    const float mu  = s1 * (1.f/768.f);
    const float var = s2 * (1.f/768.f) - mu*mu;
    const float rs  = rsqrtf(var + LN_EPS);
    #pragma unroll
    for(int i=0;i<12;i++){ const int c2 = lane + i*64; cn[r][c2] = (vals[i]-mu)*rs*tg[c2] + tb[c2]; }
  }
  __syncthreads();

  const int dq = tid & 63;
  const int part = tid >> 6;
  const float* W    = (dc < 2) ? Wk : Wv;
  const float* bias = (dc < 2) ? bk : bv;
  float* obuf       = (dc < 2) ? kbuf : vbuf;
  const int d0 = (dc & 1) * 256 + dq * 4;

  float acc[4][4] = {};
  for(int i=0;i<768;i++){
    const float4 wv = *(const float4*)(W + (size_t)i * 512 + d0);
    #pragma unroll
    for(int j=0;j<4;j++){
      const float c = cn[part*4 + j][i];
      acc[j][0] += c * wv.x; acc[j][1] += c * wv.y;
      acc[j][2] += c * wv.z; acc[j][3] += c * wv.w;
    }
  }
  #pragma unroll
  for(int j=0;j<4;j++){
    const int r = part*4 + j, n = n0 + r;
    if(r < nrows){
      float4 o;
      o.x = acc[j][0] + bias[d0+0];
      o.y = acc[j][1] + bias[d0+1];
      o.z = acc[j][2] + bias[d0+2];
      o.w = acc[j][3] + bias[d0+3];
      *(float4*)(obuf + ((size_t)bc * 77 + n) * 512 + d0) = o;
    }
  }
}

// ---------------------------------------------------------------------------
// Kernel 2: softmax K over tokens; ctxP packed in MFMA-B-frag order
// ---------------------------------------------------------------------------
__global__ void k_ctx(const float* __restrict__ kbuf, const float* __restrict__ vbuf,
                      unsigned short* __restrict__ ctxP)
{
  __shared__ float kk[77][64];
  __shared__ float vv[77][64];
  __shared__ float inv_s[64];
  const int h = blockIdx.x, bc = blockIdx.y;
  const int tid = threadIdx.x;
  for(int e = tid; e < 77*64; e += 256){
    const int n = e >> 6, c = e & 63;
    kk[n][c] = kbuf[((size_t)bc * 77 + n) * 512 + h*64 + c];
    vv[n][c] = vbuf[((size_t)bc * 77 + n) * 512 + h*64 + c];
  }
  __syncthreads();
  if(tid < 64){
    float m = -1e30f;
    for(int n=0;n<77;n++) m = fmaxf(m, kk[n][tid]);
    float s = 0.f;
    for(int n=0;n<77;n++){ const float e = __expf(kk[n][tid] - m); kk[n][tid] = e; s += e; }
    inv_s[tid] = 1.f / s;
  }
  __syncthreads();
  #pragma unroll
  for(int j=0;j<16;j++){
    const int o = tid + 256*j;
    const int v = o >> 6, k2 = o & 63;
    float a = 0.f;
    for(int n=0;n<77;n++) a += kk[n][k2] * vv[n][v];
    const int pos = ((((k2>>5)*4 + (v>>4))*4 + ((k2>>3)&3))*16 + (v&15))*8 + (k2&7);
    ctxP[((size_t)(bc*8 + h)) * 4096 + pos] = f2bf(a * inv_s[k2]);
  }
}

// ---------------------------------------------------------------------------
// Kernel 4: LN + transpose + bf16, slot-swizzled xT (R4-validated).
// grid (128, 32): y<24 lnt role; y>=24 copy role for non-cond batches.
// ---------------------------------------------------------------------------
__global__ __launch_bounds__(256, 2)
void k_lnt(const float* __restrict__ input, const int* __restrict__ idx,
           const float* __restrict__ ln_g, const float* __restrict__ ln_b,
           unsigned short* __restrict__ xT, float* __restrict__ out)
{
  __shared__ float buf[32][516];
  __shared__ float red1[32][8], red2[32][8];
  __shared__ float mu_s[32], rs_s[32];
  __shared__ float gbuf[512], bbuf[512];

  const int tid = threadIdx.x;

  if(blockIdx.y >= 24){
    // ---- copy role: 8 non-cond batches x 128 chunks ----
    const int nb = blockIdx.y - 24;
    int cnt = 0, bsel = 0;
    for(int b2 = 0; b2 < 32; ++b2){
      bool member = false;
      #pragma unroll
      for(int i2 = 0; i2 < 24; ++i2) member |= (idx[i2] == b2);
      if(!member){ if(cnt == nb) bsel = b2; ++cnt; }
    }
    const float4* s = (const float4*)(input + (size_t)bsel * 2097152) + (size_t)blockIdx.x * 4096;
    float4*       d = (float4*)      (out   + (size_t)bsel * 2097152) + (size_t)blockIdx.x * 4096;
    #pragma unroll
    for(int i = 0; i < 16; ++i) d[i*256 + tid] = s[i*256 + tid];
    return;
  }

  const int bc = blockIdx.y;
  const int b  = idx[bc];
  const int t0 = blockIdx.x * 32;
  const float* xb = input + (size_t)b * (512*4096) + t0;

  *(float2*)&gbuf[tid*2] = *(const float2*)&ln_g[tid*2];
  *(float2*)&bbuf[tid*2] = *(const float2*)&ln_b[tid*2];

  {
    const int p  = tid & 7;
    const int dg = tid >> 3;
    #pragma unroll
    for(int i=0;i<16;i++){
      const int d = dg + i*32;
      const float4 x = *(const float4*)(xb + (size_t)d * 4096 + p*4);
      buf[p*4+0][d] = x.x; buf[p*4+1][d] = x.y;
      buf[p*4+2][d] = x.z; buf[p*4+3][d] = x.w;
    }
  }
  __syncthreads();

  {
    const int t = tid & 31, part = tid >> 5;
    float s1 = 0.f, s2 = 0.f;
    #pragma unroll
    for(int i=0;i<16;i++){
      const float4 v = *(const float4*)&buf[t][part*64 + i*4];
      s1 += v.x+v.y+v.z+v.w;
      s2 += v.x*v.x + v.y*v.y + v.z*v.z + v.w*v.w;
    }
    red1[t][part] = s1; red2[t][part] = s2;
  }
  __syncthreads();
  if(tid < 32){
    float a = 0.f, c = 0.f;
    #pragma unroll
    for(int p=0;p<8;p++){ a += red1[tid][p]; c += red2[tid][p]; }
    const float mu  = a * (1.f/512.f);
    const float var = c * (1.f/512.f) - mu*mu;
    mu_s[tid] = mu; rs_s[tid] = rsqrtf(var + LN_EPS);
  }
  __syncthreads();

  {
    const int c  = tid & 7;
    const int tt = tid >> 3;
    const float mu = mu_s[tt], rs = rs_s[tt];
    const int swz = (tt >> 1) & 3;
    unsigned short* orow = xT + ((size_t)bc*4096 + t0 + tt) * 512;
    #pragma unroll
    for(int j=0;j<8;j++){
      const int d0 = c*8 + j*64;
      const float4 a  = *(const float4*)&buf[tt][d0];
      const float4 b4 = *(const float4*)&buf[tt][d0+4];
      const float4 g0 = *(const float4*)&gbuf[d0];
      const float4 g1 = *(const float4*)&gbuf[d0+4];
      const float4 h0 = *(const float4*)&bbuf[d0];
      const float4 h1 = *(const float4*)&bbuf[d0+4];
      s16x8 o;
      o[0] = (short)f2bf((a.x -mu)*rs*g0.x + h0.x);
      o[1] = (short)f2bf((a.y -mu)*rs*g0.y + h0.y);
      o[2] = (short)f2bf((a.z -mu)*rs*g0.z + h0.z);
      o[3] = (short)f2bf((a.w -mu)*rs*g0.w + h0.w);
      o[4] = (short)f2bf((b4.x-mu)*rs*g1.x + h1.x);
      o[5] = (short)f2bf((b4.y-mu)*rs*g1.y + h1.y);
      o[6] = (short)f2bf((b4.z-mu)*rs*g1.z + h1.z);
      o[7] = (short)f2bf((b4.w-mu)*rs*g1.w + h1.w);
      *(s16x8*)(orow + (d0 ^ (swz << 3))) = o;
    }
  }
}

// ---------------------------------------------------------------------------
// Kernel 5: 128x128 MFMA GEMM, TRIPLE-buffered gll16 staging with counted
// vmcnt(4) (never drains in-loop), 1 barrier/step; swizzled LDS; fused
// softmax / PV / float4 residual epilogue. (R4 structure + T3/T4-lite loop)
// grid (4 ntile, 768 mtile), 256 threads (4 waves, 2x2).
// ---------------------------------------------------------------------------
__global__ __launch_bounds__(256, 3)
void k_gemm3(const float* __restrict__ input, const int* __restrict__ idx,
             const unsigned short* __restrict__ xT, const unsigned short* __restrict__ WqT,
             const float* __restrict__ bq, const unsigned short* __restrict__ ctxP,
             float* __restrict__ out)
{
  __shared__ __align__(16) char smem[49152];   // 3 x (A 8KB + B 8KB)
  unsigned short* P = (unsigned short*)smem;   // [4][64][72] aliased after K-loop

  const int tid  = threadIdx.x;
  const int lane = tid & 63;
  const int w    = tid >> 6;
  const int col  = lane & 15;
  const int g    = lane >> 4;
  const int wm   = w >> 1, wn = w & 1;
  const int ntile = blockIdx.x, mtile = blockIdx.y;
  const int bc   = mtile >> 5;
  const int tt0  = (mtile & 31) * 128;
  const int b    = idx[bc];
  const int nbase = ntile * 128;
  const char* xTb = (const char*)xT + ((size_t)bc*4096 + tt0) * 1024;
  const char* wTb = (const char*)WqT + (size_t)nbase * 1024;

  const int f0 = tid * 16;
  const int f1 = f0 + 4096;
  const int r0 = f0 >> 6, o0 = f0 & 63;
  const int r1 = f1 >> 6, o1 = f1 & 63;

  #define STAGE(ks, bi)                                                   \
  {                                                                       \
    char* dst = smem + (bi)*16384;                                        \
    gll16(xTb + (size_t)r0*1024 + (ks)*64 + o0, dst + f0);                \
    gll16(xTb + (size_t)r1*1024 + (ks)*64 + o1, dst + f1);                \
    gll16(wTb + (size_t)r0*1024 + (ks)*64 + o0, dst + 8192 + f0);         \
    gll16(wTb + (size_t)r1*1024 + (ks)*64 + o1, dst + 8192 + f1);         \
  }

  f32x4 acc[4][4] = {};

  int offA[4], offB[4];
  #pragma unroll
  for(int mt=0; mt<4; ++mt){
    const int rowA = wm*64 + mt*16 + col;
    offA[mt] = rowA*64 + ((g ^ ((rowA>>1)&3)) << 4);
    const int rowB = wn*64 + mt*16 + col;
    offB[mt] = rowB*64 + ((g ^ ((rowB>>1)&3)) << 4);
  }

  STAGE(0, 0);
  STAGE(1, 1);

  #pragma unroll
  for(int ks=0; ks<16; ++ks){
    // wait for buf[ks%3]'s 4 loads (2-deep pipeline: <=8 outstanding -> 4)
    if(ks < 15) asm volatile("s_waitcnt vmcnt(4)" ::: "memory");
    else        asm volatile("s_waitcnt vmcnt(0)" ::: "memory");
    __builtin_amdgcn_s_barrier();
    // prefetch 2 steps ahead (writes buf[(ks+2)%3] = buf[(ks-1)%3], WAR-safe:
    // all waves retired their (ks-1) reads before this barrier)
    if(ks < 14) STAGE(ks+2, (ks+2)%3);

    char* cur = smem + (ks%3)*16384;
    bf16x8 af[4], bfr[4];
    #pragma unroll
    for(int mt=0; mt<4; ++mt) af[mt]  = *(const bf16x8*)(cur + offA[mt]);
    #pragma unroll
    for(int nt=0; nt<4; ++nt) bfr[nt] = *(const bf16x8*)(cur + 8192 + offB[nt]);
    #pragma unroll
    for(int mt=0; mt<4; ++mt)
      #pragma unroll
      for(int nt=0; nt<4; ++nt)
        acc[mt][nt] = __builtin_amdgcn_mfma_f32_16x16x32_bf16(af[mt], bfr[nt], acc[mt][nt], 0, 0, 0);
  }
  #undef STAGE
  __syncthreads();   // all waves done reading buffers before P aliases them

  // ---- bias + per-head feature softmax (wave owns one head) ----
  #pragma unroll
  for(int mt=0; mt<4; ++mt){
    #pragma unroll
    for(int nt=0; nt<4; ++nt){
      const float bqv = bq[nbase + wn*64 + nt*16 + col];
      #pragma unroll
      for(int r=0;r<4;++r) acc[mt][nt][r] += bqv;
    }
    #pragma unroll
    for(int r=0;r<4;++r){
      float m = fmaxf(fmaxf(acc[mt][0][r],acc[mt][1][r]), fmaxf(acc[mt][2][r],acc[mt][3][r]));
      m = fmaxf(m, __shfl_xor(m, 1));
      m = fmaxf(m, __shfl_xor(m, 2));
      m = fmaxf(m, __shfl_xor(m, 4));
      m = fmaxf(m, __shfl_xor(m, 8));
      float s = 0.f;
      #pragma unroll
      for(int q=0;q<4;++q){
        const float e = __expf(acc[mt][q][r] - m);
        acc[mt][q][r] = e; s += e;
      }
      s += __shfl_xor(s, 1);
      s += __shfl_xor(s, 2);
      s += __shfl_xor(s, 4);
      s += __shfl_xor(s, 8);
      const float inv = 1.f / s;
      #pragma unroll
      for(int q=0;q<4;++q) acc[mt][q][r] *= inv;
    }
  }

  // ---- P store (wave-private region) ----
  unsigned short* Pw = P + w * 64 * 72;
  #pragma unroll
  for(int mt=0; mt<4; ++mt)
    #pragma unroll
    for(int nt=0; nt<4; ++nt)
      #pragma unroll
      for(int r=0; r<4; ++r)
        Pw[(mt*16 + g*4 + r)*72 + nt*16 + col] = f2bf(acc[mt][nt][r]);

  // ---- PV: y[t][v] = sum_k P[t][k] * ctx[k][v] ----
  const int head = ntile*2 + wn;
  const unsigned short* cp = ctxP + (size_t)(bc*8 + head) * 4096;
  f32x4 y[4][4] = {};
  #pragma unroll
  for(int ks2=0; ks2<2; ++ks2){
    bf16x8 pa[4];
    #pragma unroll
    for(int mt=0; mt<4; ++mt)
      pa[mt] = *(const bf16x8*)(Pw + (mt*16 + col)*72 + ks2*32 + g*8);
    bf16x8 cv[4];
    #pragma unroll
    for(int vt=0; vt<4; ++vt)
      cv[vt] = *(const bf16x8*)(cp + (size_t)(((ks2*4 + vt)*4 + g)*16 + col) * 8);
    #pragma unroll
    for(int mt=0; mt<4; ++mt)
      #pragma unroll
      for(int vt=0; vt<4; ++vt)
        y[mt][vt] = __builtin_amdgcn_mfma_f32_16x16x32_bf16(pa[mt], cv[vt], y[mt][vt], 0, 0, 0);
  }

  // ---- residual + store (float4 along t) ----
  const float* xb = input + (size_t)b * 2097152;
  float*       ob = out   + (size_t)b * 2097152;
  #pragma unroll
  for(int mt=0; mt<4; ++mt)
    #pragma unroll
    for(int vt=0; vt<4; ++vt){
      const size_t a = (size_t)(head*64 + vt*16 + col)*4096
                     + (size_t)(tt0 + wm*64 + mt*16 + g*4);
      const float4 xr = *(const float4*)(xb + a);
      float4 o4;
      o4.x = xr.x + y[mt][vt][0];
      o4.y = xr.y + y[mt][vt][1];
      o4.z = xr.z + y[mt][vt][2];
      o4.w = xr.w + y[mt][vt][3];
      *(float4*)(ob + a) = o4;
    }
}

// ---------------------------------------------------------------------------
extern "C" void kernel_launch(void* const* d_in, const int* in_sizes, int n_in,
                              void* d_out, int out_size, void* d_ws, size_t ws_size,
                              hipStream_t stream)
{
  const float* input = (const float*)d_in[0];
  const float* cond  = (const float*)d_in[1];
  const int*   idx   = (const int*)d_in[2];
  const float* ln_g  = (const float*)d_in[3];
  const float* ln_b  = (const float*)d_in[4];
  const float* tln_g = (const float*)d_in[5];
  const float* tln_b = (const float*)d_in[6];
  const float* Wq    = (const float*)d_in[7];
  const float* bq    = (const float*)d_in[8];
  const float* Wk    = (const float*)d_in[9];
  const float* bk    = (const float*)d_in[10];
  const float* Wv    = (const float*)d_in[11];
  const float* bv    = (const float*)d_in[12];
  float* out = (float*)d_out;
  char*  ws  = (char*)d_ws;

  unsigned short* WqT  = (unsigned short*)(ws);                     // 512 KB
  unsigned short* ctxP = (unsigned short*)(ws + 524288);            // 1.5 MB
  float* kbuf = (float*)(ws + 2097152);                             // 3.61 MB
  float* vbuf = (float*)(ws + 2097152 + 3784704);                   // 3.61 MB
  unsigned short* xT = (unsigned short*)(ws + 2097152 + 2*3784704); // 96 MB

  k_aux  <<<dim3(4,5,25),  dim3(256), 0, stream>>>(Wq, WqT, cond, idx, tln_g, tln_b,
                                                   Wk, bk, Wv, bv, kbuf, vbuf);
  k_ctx  <<<dim3(8,24),    dim3(256), 0, stream>>>(kbuf, vbuf, ctxP);
  k_lnt  <<<dim3(128,32),  dim3(256), 0, stream>>>(input, idx, ln_g, ln_b, xT, out);
  k_gemm3<<<dim3(4,768),   dim3(256), 0, stream>>>(input, idx, xT, WqT, bq, ctxP, out);
}

// Round 9
// 439.538 us; speedup vs baseline: 1.0214x; 1.0214x over previous
//
#include <hip/hip_runtime.h>

#define LN_EPS 1e-5f

typedef __attribute__((ext_vector_type(8))) short bf16x8;
typedef __attribute__((ext_vector_type(4))) float f32x4;

__device__ __forceinline__ unsigned short f2bf(float f){
  unsigned u = __builtin_bit_cast(unsigned, f);
  u = (u + 0x7fffu + ((u >> 16) & 1u)) >> 16;
  return (unsigned short)u;
}
__device__ __forceinline__ float bf2f(unsigned short h){
  unsigned u = ((unsigned)h) << 16;
  return __builtin_bit_cast(float, u);
}

// ---------------------------------------------------------------------------
// Kernel A (merged): z<24 -> cond LN + K/V projection; z==24 -> gWq prep.
//  gWqT[n][d] = bf16(g[d]*Wq[d][n])  (plain layout)
//  c12[n] = { sum_d b[d]*Wq[d][n] + bq[n],  sum_d bf16(g*W)[d][n] }
// ---------------------------------------------------------------------------
__global__ void k_aux(const float* __restrict__ Wq, const float* __restrict__ ln_g,
                      const float* __restrict__ ln_b, const float* __restrict__ bq,
                      unsigned short* __restrict__ gWqT, float2* __restrict__ c12,
                      const float* __restrict__ cond, const int* __restrict__ idx,
                      const float* __restrict__ tg, const float* __restrict__ tb,
                      const float* __restrict__ Wk, const float* __restrict__ bk,
                      const float* __restrict__ Wv, const float* __restrict__ bv,
                      float* __restrict__ kbuf, float* __restrict__ vbuf)
{
  __shared__ float cn[16][768];
  const int tid = threadIdx.x;

  if(blockIdx.z == 24){
    const int pb = blockIdx.x + 4*blockIdx.y;
    if(pb >= 8) return;
    float* const r1 = &cn[0][0];
    float* const r2 = &cn[0][0] + 256;
    const int n0 = pb * 64;
    const int c = tid & 63, q = tid >> 6;
    const int n = n0 + c;
    float c1p = 0.f, c2p = 0.f;
    for(int i=0;i<128;i+=4){
      ushort4 pkv;
      unsigned short* pp = (unsigned short*)&pkv;
      #pragma unroll
      for(int j=0;j<4;j++){
        const int d = q*128 + i + j;
        const float wv = Wq[(size_t)d*512 + n];
        const unsigned short hb = f2bf(ln_g[d] * wv);
        pp[j] = hb;
        c2p += bf2f(hb);
        c1p += ln_b[d] * wv;
      }
      *(ushort4*)(gWqT + (size_t)n*512 + q*128 + i) = pkv;
    }
    r1[c*4 + q] = c1p; r2[c*4 + q] = c2p;
    __syncthreads();
    if(q == 0){
      float a = 0.f, b2 = 0.f;
      #pragma unroll
      for(int j=0;j<4;j++){ a += r1[c*4+j]; b2 += r2[c*4+j]; }
      c12[n] = make_float2(a + bq[n], b2);
    }
    return;
  }

  // ---- condkv role (validated) ----
  const int bc = blockIdx.z, nc = blockIdx.y, dc = blockIdx.x;
  const int b = idx[bc];
  const int n0 = nc * 16;
  int nrows = 77 - n0; if(nrows > 16) nrows = 16;
  const int w = tid >> 6, lane = tid & 63;

  for(int r = w; r < nrows; r += 4){
    const float* src = cond + ((size_t)b * 77 + n0 + r) * 768;
    float vals[12]; float s1 = 0.f, s2 = 0.f;
    #pragma unroll
    for(int i=0;i<12;i++){ float x = src[lane + i*64]; vals[i]=x; s1+=x; s2+=x*x; }
    #pragma unroll
    for(int off=1; off<64; off<<=1){ s1 += __shfl_xor(s1, off); s2 += __shfl_xor(s2, off); }
    const float mu  = s1 * (1.f/768.f);
    const float var = s2 * (1.f/768.f) - mu*mu;
    const float rs  = rsqrtf(var + LN_EPS);
    #pragma unroll
    for(int i=0;i<12;i++){ const int c2 = lane + i*64; cn[r][c2] = (vals[i]-mu)*rs*tg[c2] + tb[c2]; }
  }
  __syncthreads();

  const int dq = tid & 63;
  const int part = tid >> 6;
  const float* W    = (dc < 2) ? Wk : Wv;
  const float* bias = (dc < 2) ? bk : bv;
  float* obuf       = (dc < 2) ? kbuf : vbuf;
  const int d0 = (dc & 1) * 256 + dq * 4;

  float acc[4][4] = {};
  for(int i=0;i<768;i++){
    const float4 wv = *(const float4*)(W + (size_t)i * 512 + d0);
    #pragma unroll
    for(int j=0;j<4;j++){
      const float c = cn[part*4 + j][i];
      acc[j][0] += c * wv.x; acc[j][1] += c * wv.y;
      acc[j][2] += c * wv.z; acc[j][3] += c * wv.w;
    }
  }
  #pragma unroll
  for(int j=0;j<4;j++){
    const int r = part*4 + j, n = n0 + r;
    if(r < nrows){
      float4 o;
      o.x = acc[j][0] + bias[d0+0];
      o.y = acc[j][1] + bias[d0+1];
      o.z = acc[j][2] + bias[d0+2];
      o.w = acc[j][3] + bias[d0+3];
      *(float4*)(obuf + ((size_t)bc * 77 + n) * 512 + d0) = o;
    }
  }
}

// ---------------------------------------------------------------------------
// Kernel 2: softmax K over tokens; ctxP packed in MFMA-B-frag order
// ---------------------------------------------------------------------------
__global__ void k_ctx(const float* __restrict__ kbuf, const float* __restrict__ vbuf,
                      unsigned short* __restrict__ ctxP)
{
  __shared__ float kk[77][64];
  __shared__ float vv[77][64];
  __shared__ float inv_s[64];
  const int h = blockIdx.x, bc = blockIdx.y;
  const int tid = threadIdx.x;
  for(int e = tid; e < 77*64; e += 256){
    const int n = e >> 6, c = e & 63;
    kk[n][c] = kbuf[((size_t)bc * 77 + n) * 512 + h*64 + c];
    vv[n][c] = vbuf[((size_t)bc * 77 + n) * 512 + h*64 + c];
  }
  __syncthreads();
  if(tid < 64){
    float m = -1e30f;
    for(int n=0;n<77;n++) m = fmaxf(m, kk[n][tid]);
    float s = 0.f;
    for(int n=0;n<77;n++){ const float e = __expf(kk[n][tid] - m); kk[n][tid] = e; s += e; }
    inv_s[tid] = 1.f / s;
  }
  __syncthreads();
  #pragma unroll
  for(int j=0;j<16;j++){
    const int o = tid + 256*j;
    const int v = o >> 6, k2 = o & 63;
    float a = 0.f;
    for(int n=0;n<77;n++) a += kk[n][k2] * vv[n][v];
    const int pos = ((((k2>>5)*4 + (v>>4))*4 + ((k2>>3)&3))*16 + (v&15))*8 + (k2&7);
    ctxP[((size_t)(bc*8 + h)) * 4096 + pos] = f2bf(a * inv_s[k2]);
  }
}

// ---------------------------------------------------------------------------
// Kernel 3: k_fuse — whole-tile upfront staging + barrier-free K-loop.
// Block = 64 t x 256 n (4 waves, wave = one head). grid (2 ntile, 1792).
// Phase 0: read raw x[512d][64t] ONCE -> bf16 micro-transpose -> 64KB LDS
//          (XOR-swizzled), LN stats from fp32 regs concurrently.
// K-loop:  16 steps, NO barriers, NO staging: A from LDS, B(W) direct from
//          L2-resident gWqT; MFMA.
// Epilogue: LN fold (q = rs*G - rs*mu*c2 + c1), per-head softmax, P->LDS
//          (aliases X), PV MFMA vs ctxP, float4 residual store.
// ---------------------------------------------------------------------------
__global__ __launch_bounds__(256, 2)
void k_fuse(const float* __restrict__ input, const int* __restrict__ idx,
            const unsigned short* __restrict__ gWqT, const float2* __restrict__ c12,
            const unsigned short* __restrict__ ctxP, float* __restrict__ out)
{
  const int nt  = blockIdx.x;
  const int by  = blockIdx.y;
  const int tid = threadIdx.x;

  if(by >= 1536){
    const int cid = (by - 1536)*2 + nt;     // 0..511
    const int nb = cid >> 6, chunk = cid & 63;
    int cnt = 0, bsel = 0;
    for(int b2 = 0; b2 < 32; ++b2){
      bool member = false;
      #pragma unroll
      for(int i2 = 0; i2 < 24; ++i2) member |= (idx[i2] == b2);
      if(!member){ if(cnt == nb) bsel = b2; ++cnt; }
    }
    const float4* s = (const float4*)(input + (size_t)bsel * 2097152) + chunk*8192;
    float4*       d = (float4*)      (out   + (size_t)bsel * 2097152) + chunk*8192;
    #pragma unroll
    for(int i = 0; i < 32; ++i) d[i*256 + tid] = s[i*256 + tid];
    return;
  }

  __shared__ __align__(16) char smem[68096];
  // X @0: [64 t][512 k] bf16, 1024B rows, slot16 swizzle s=(k>>3)^(t&7). 65536B.
  // P aliases X: wave w @ w*8192, [64][64] bf16 swizzled, 128B rows.
  // red1 @65536 [64][4]; red2 @66560 [64][4]; mu @67584; rs @67840.
  float* const red1 = (float*)(smem + 65536);
  float* const red2 = (float*)(smem + 66560);
  float* const mu_s = (float*)(smem + 67584);
  float* const rs_s = (float*)(smem + 67840);

  const int lane = tid & 63, w = tid >> 6;
  const int col = lane & 15, g = lane >> 4;
  const int bc = by >> 6, b = idx[bc];
  const int t0 = (by & 63) * 64;
  const int nbase = nt * 256;
  const float* xb = input + (size_t)b * 2097152;

  // ---- phase 0: stage bf16(x) tile + LN stats ----
  const int tq = tid & 15;            // t-quad: t = tq*4+j
  const int dq = tid >> 4;            // 0..15
  const float* xcol = xb + t0 + tq*4;

  float s1[4] = {0,0,0,0}, s2[4] = {0,0,0,0};
  #pragma unroll 2
  for(int p = 0; p < 8; ++p){
    const int d0 = p*64 + dq*4;
    float4 xr[4];
    #pragma unroll
    for(int di=0; di<4; ++di) xr[di] = *(const float4*)(xcol + (size_t)(d0+di)*4096);
    #pragma unroll
    for(int j=0; j<4; ++j){
      const float v0 = (&xr[0].x)[j], v1 = (&xr[1].x)[j];
      const float v2 = (&xr[2].x)[j], v3 = (&xr[3].x)[j];
      s1[j] += v0+v1+v2+v3;
      s2[j] += v0*v0 + v1*v1 + v2*v2 + v3*v3;
      const int t = tq*4 + j;
      const int byteo = t*1024 + ((((d0>>3) ^ (t&7)))<<4) + ((d0&7)<<1);
      *(ushort4*)(smem + byteo) = make_ushort4(f2bf(v0), f2bf(v1), f2bf(v2), f2bf(v3));
    }
  }
  // stats reduce: shfl over dq&3 within wave, LDS across waves
  #pragma unroll
  for(int j=0;j<4;j++){
    s1[j] += __shfl_xor(s1[j], 16); s2[j] += __shfl_xor(s2[j], 16);
    s1[j] += __shfl_xor(s1[j], 32); s2[j] += __shfl_xor(s2[j], 32);
  }
  if(lane < 16){
    #pragma unroll
    for(int j=0;j<4;j++){
      red1[(lane*4 + j)*4 + w] = s1[j];
      red2[(lane*4 + j)*4 + w] = s2[j];
    }
  }
  __syncthreads();
  if(tid < 64){
    const float a  = red1[tid*4] + red1[tid*4+1] + red1[tid*4+2] + red1[tid*4+3];
    const float c2 = red2[tid*4] + red2[tid*4+1] + red2[tid*4+2] + red2[tid*4+3];
    const float mu  = a * (1.f/512.f);
    const float var = c2 * (1.f/512.f) - mu*mu;
    mu_s[tid] = mu;
    rs_s[tid] = rsqrtf(var + LN_EPS);
  }
  __syncthreads();

  // ---- K-loop: barrier-free. A from LDS, W direct from L2. ----
  int rowp[4], row7[4];
  #pragma unroll
  for(int mt=0; mt<4; ++mt){
    const int row = mt*16 + col;
    rowp[mt] = row*1024;
    row7[mt] = row & 7;
  }
  const char* wrow[4];
  #pragma unroll
  for(int ntl=0; ntl<4; ++ntl)
    wrow[ntl] = (const char*)gWqT + (size_t)(nbase + w*64 + ntl*16 + col)*1024 + g*16;

  f32x4 acc[4][4] = {};
  #pragma unroll 4
  for(int ks=0; ks<16; ++ks){
    bf16x8 wf[4], af[4];
    #pragma unroll
    for(int ntl=0; ntl<4; ++ntl) wf[ntl] = *(const bf16x8*)(wrow[ntl] + ks*64);
    #pragma unroll
    for(int mt=0; mt<4; ++mt)
      af[mt] = *(const bf16x8*)(smem + rowp[mt] + (((ks*4 + g) ^ row7[mt]) << 4));
    #pragma unroll
    for(int mt=0; mt<4; ++mt)
      #pragma unroll
      for(int ntl=0; ntl<4; ++ntl)
        acc[mt][ntl] = __builtin_amdgcn_mfma_f32_16x16x32_bf16(af[mt], wf[ntl], acc[mt][ntl], 0, 0, 0);
  }

  // ---- LN fold + per-head feature softmax (wave owns one head) ----
  const int head = nt*4 + w;
  float c1b[4], c2v[4];
  #pragma unroll
  for(int ntl=0; ntl<4; ++ntl){
    const float2 cc = c12[nbase + w*64 + ntl*16 + col];
    c1b[ntl] = cc.x;   // includes bq
    c2v[ntl] = cc.y;
  }
  #pragma unroll
  for(int mt=0; mt<4; ++mt){
    #pragma unroll
    for(int r=0; r<4; ++r){
      const int tl = mt*16 + g*4 + r;
      const float rsr = rs_s[tl];
      const float mrc = rsr * mu_s[tl];
      float v[4];
      #pragma unroll
      for(int ntl=0; ntl<4; ++ntl)
        v[ntl] = rsr*acc[mt][ntl][r] - mrc*c2v[ntl] + c1b[ntl];
      float m = fmaxf(fmaxf(v[0],v[1]), fmaxf(v[2],v[3]));
      m = fmaxf(m, __shfl_xor(m, 1));
      m = fmaxf(m, __shfl_xor(m, 2));
      m = fmaxf(m, __shfl_xor(m, 4));
      m = fmaxf(m, __shfl_xor(m, 8));
      float s = 0.f;
      #pragma unroll
      for(int ntl=0; ntl<4; ++ntl){ v[ntl] = __expf(v[ntl] - m); s += v[ntl]; }
      s += __shfl_xor(s, 1);
      s += __shfl_xor(s, 2);
      s += __shfl_xor(s, 4);
      s += __shfl_xor(s, 8);
      const float inv = 1.f / s;
      #pragma unroll
      for(int ntl=0; ntl<4; ++ntl) acc[mt][ntl][r] = v[ntl] * inv;
    }
  }

  __syncthreads();   // all waves done reading X before P aliases it

  // ---- P -> LDS (wave-private, swizzled [64][64]) ----
  char* const Pw = smem + w * 8192;
  #pragma unroll
  for(int mt=0; mt<4; ++mt)
    #pragma unroll
    for(int ntl=0; ntl<4; ++ntl)
      #pragma unroll
      for(int r=0; r<4; ++r){
        const int row = mt*16 + g*4 + r;
        const int k   = ntl*16 + col;
        const int byteo = row*128 + ((((k>>3) ^ (row&7)))<<4) + ((k&7)<<1);
        *(unsigned short*)(Pw + byteo) = f2bf(acc[mt][ntl][r]);
      }

  // ---- PV MFMA vs ctxP ----
  const unsigned short* cp = ctxP + (size_t)(bc*8 + head) * 4096;
  f32x4 y[4][4] = {};
  #pragma unroll
  for(int ks2=0; ks2<2; ++ks2){
    bf16x8 pa[4];
    #pragma unroll
    for(int mt=0; mt<4; ++mt){
      const int row = mt*16 + col;
      pa[mt] = *(const bf16x8*)(Pw + row*128 + ((((ks2*4 + g) ^ (row&7)))<<4));
    }
    bf16x8 cv[4];
    #pragma unroll
    for(int vt=0; vt<4; ++vt)
      cv[vt] = *(const bf16x8*)(cp + (size_t)(((ks2*4 + vt)*4 + g)*16 + col) * 8);
    #pragma unroll
    for(int mt=0; mt<4; ++mt)
      #pragma unroll
      for(int vt=0; vt<4; ++vt)
        y[mt][vt] = __builtin_amdgcn_mfma_f32_16x16x32_bf16(pa[mt], cv[vt], y[mt][vt], 0, 0, 0);
  }

  // ---- residual + float4 store ----
  float* const ob = out + (size_t)b * 2097152;
  #pragma unroll
  for(int mt=0; mt<4; ++mt)
    #pragma unroll
    for(int vt=0; vt<4; ++vt){
      const size_t a = (size_t)(head*64 + vt*16 + col)*4096
                     + (size_t)(t0 + mt*16 + g*4);
      const float4 xr4 = *(const float4*)(xb + a);
      float4 o4;
      o4.x = xr4.x + y[mt][vt][0];
      o4.y = xr4.y + y[mt][vt][1];
      o4.z = xr4.z + y[mt][vt][2];
      o4.w = xr4.w + y[mt][vt][3];
      *(float4*)(ob + a) = o4;
    }
}

// ---------------------------------------------------------------------------
extern "C" void kernel_launch(void* const* d_in, const int* in_sizes, int n_in,
                              void* d_out, int out_size, void* d_ws, size_t ws_size,
                              hipStream_t stream)
{
  const float* input = (const float*)d_in[0];
  const float* cond  = (const float*)d_in[1];
  const int*   idx   = (const int*)d_in[2];
  const float* ln_g  = (const float*)d_in[3];
  const float* ln_b  = (const float*)d_in[4];
  const float* tln_g = (const float*)d_in[5];
  const float* tln_b = (const float*)d_in[6];
  const float* Wq    = (const float*)d_in[7];
  const float* bq    = (const float*)d_in[8];
  const float* Wk    = (const float*)d_in[9];
  const float* bk    = (const float*)d_in[10];
  const float* Wv    = (const float*)d_in[11];
  const float* bv    = (const float*)d_in[12];
  float* out = (float*)d_out;
  char*  ws  = (char*)d_ws;

  unsigned short* gWqT = (unsigned short*)(ws);                  // 512 KB
  float2*         c12  = (float2*)(ws + 524288);                 // 4 KB
  unsigned short* ctxP = (unsigned short*)(ws + 528384);         // 1.5 MB
  float* kbuf = (float*)(ws + 2101248);                          // 3.61 MB
  float* vbuf = (float*)(ws + 2101248 + 3784704);                // 3.61 MB

  k_aux <<<dim3(4,5,25),  dim3(256), 0, stream>>>(Wq, ln_g, ln_b, bq, gWqT, c12,
                                                  cond, idx, tln_g, tln_b,
                                                  Wk, bk, Wv, bv, kbuf, vbuf);
  k_ctx <<<dim3(8,24),    dim3(256), 0, stream>>>(kbuf, vbuf, ctxP);
  k_fuse<<<dim3(2,1792),  dim3(256), 0, stream>>>(input, idx, gWqT, c12, ctxP, out);
}